// Round 1
// baseline (101.737 us; speedup 1.0000x reference)
//
#include <hip/hip_runtime.h>

// YOLO decode = batched [255 x 5776] transpose + elementwise, LDS-tiled.
// B=32, A=3, C=80 -> attrs=85, CH=255, G=76, SP=5776, stride=8.

#define BATCH   32
#define ATTRS   85
#define CH      255          // A * attrs
#define GRID    76
#define SP      5776         // GRID*GRID
#define STRIDE_F 8.0f
#define S_TILE  32
#define TPB     256
#define TILES_PER_B ((SP + S_TILE - 1) / S_TILE)   // 181 (180 full + one 16-wide)
#define NF4_READ (CH * (S_TILE / 4))               // 255 * 8 = 2040

__global__ __launch_bounds__(TPB) void yolo_decode_kernel(
        const float* __restrict__ pred,
        const float* __restrict__ anchors,
        float* __restrict__ out) {
    __shared__ float lds[S_TILE * CH];   // transposed tile: [s_local][c]
    __shared__ float s_anc[6];

    const int tid = threadIdx.x;
    const int bid = blockIdx.x;
    const int b   = bid / TILES_PER_B;
    const int t   = bid - b * TILES_PER_B;
    const int s0  = t * S_TILE;

    if (tid < 6) s_anc[tid] = anchors[tid];
    __syncthreads();

    const int sw = (SP - s0 < S_TILE) ? (SP - s0) : S_TILE;  // 32, or 16 on last tile

    // ---- read phase: coalesced float4 loads along spatial, decode, scatter to LDS ----
    const float* __restrict__ src = pred + (size_t)b * (size_t)(CH * SP);
    for (int j = tid; j < NF4_READ; j += TPB) {
        const int c  = j >> 3;          // j / (S_TILE/4)
        const int s4 = j & 7;
        const int sl = s4 * 4;
        if (sl >= sw) continue;         // only trims on the 16-wide partial tile

        float4 v = *(const float4*)(src + c * SP + s0 + sl);

        const int a    = c / ATTRS;
        const int attr = c - a * ATTRS;
        const float ax = s_anc[2 * a];
        const float ay = s_anc[2 * a + 1];

        #pragma unroll
        for (int e = 0; e < 4; ++e) {
            const float val = (e == 0) ? v.x : (e == 1) ? v.y : (e == 2) ? v.z : v.w;
            const int   s   = s0 + sl + e;
            float r;
            if (attr == 2) {
                r = __expf(val) * ax;
            } else if (attr == 3) {
                r = __expf(val) * ay;
            } else {
                const float sg = 1.0f / (1.0f + __expf(-val));
                if (attr == 0) {
                    const int x = s % GRID;
                    r = (sg + (float)x) * STRIDE_F;
                } else if (attr == 1) {
                    const int y = s / GRID;
                    r = (sg + (float)y) * STRIDE_F;
                } else {
                    r = sg;
                }
            }
            lds[(sl + e) * CH + c] = r;
        }
    }
    __syncthreads();

    // ---- write phase: output tile is one contiguous [sw*255] float region ----
    const int nf4w = (sw * CH) >> 2;    // 2040 full tile, 1020 partial; both exact
    float* __restrict__ dst = out + (size_t)b * (size_t)(SP * CH) + (size_t)s0 * CH;
    for (int j = tid; j < nf4w; j += TPB) {
        float4 v = *(const float4*)(lds + j * 4);
        *(float4*)(dst + j * 4) = v;
    }
}

extern "C" void kernel_launch(void* const* d_in, const int* in_sizes, int n_in,
                              void* d_out, int out_size, void* d_ws, size_t ws_size,
                              hipStream_t stream) {
    const float* pred    = (const float*)d_in[0];
    const float* anchors = (const float*)d_in[1];
    float* out = (float*)d_out;

    const int grid = BATCH * TILES_PER_B;   // 32 * 181 = 5792 blocks
    yolo_decode_kernel<<<grid, TPB, 0, stream>>>(pred, anchors, out);
}

// Round 2
// 86.316 us; speedup vs baseline: 1.1787x; 1.1787x over previous
//
#include <hip/hip_runtime.h>

// YOLO decode = batched [255 x 5776] transpose + elementwise, LDS-tiled.
// B=32, A=3, C=80 -> attrs=85, CH=255, G=76, SP=5776, stride=8.
// R2: S_TILE=16 (16KB LDS -> 8 blocks/CU), fast-rcp sigmoid, no anchor LDS.

#define BATCH   32
#define ATTRS   85
#define CH      255          // A * attrs
#define GRID    76
#define SP      5776         // GRID*GRID; 5776 = 16 * 361 exactly
#define STRIDE_F 8.0f
#define S_TILE  16
#define TPB     256
#define TILES_PER_B (SP / S_TILE)            // 361, no partial tiles
#define NF4_READ (CH * (S_TILE / 4))         // 255 * 4 = 1020

__global__ __launch_bounds__(TPB, 8) void yolo_decode_kernel(
        const float* __restrict__ pred,
        const float* __restrict__ anchors,
        float* __restrict__ out) {
    __shared__ float lds[S_TILE * CH];   // transposed tile: [s_local][c]

    const int tid = threadIdx.x;
    const int bid = blockIdx.x;
    const int b   = bid / TILES_PER_B;
    const int t   = bid - b * TILES_PER_B;
    const int s0  = t * S_TILE;

    // anchors: 6 uniform floats -> registers (L1-hit broadcast loads)
    const float a0x = anchors[0], a0y = anchors[1];
    const float a1x = anchors[2], a1y = anchors[3];
    const float a2x = anchors[4], a2y = anchors[5];

    // ---- read phase: coalesced float4 loads along spatial, decode, scatter to LDS ----
    const float* __restrict__ src = pred + (size_t)b * (size_t)(CH * SP);
    for (int j = tid; j < NF4_READ; j += TPB) {
        const int c  = j >> 2;          // channel
        const int sl = (j & 3) * 4;     // spatial offset within tile

        float4 v = *(const float4*)(src + c * SP + s0 + sl);

        const int a    = c / ATTRS;     // 0,1,2
        const int attr = c - a * ATTRS;
        const float ax = (a == 0) ? a0x : (a == 1) ? a1x : a2x;
        const float ay = (a == 0) ? a0y : (a == 1) ? a1y : a2y;

        #pragma unroll
        for (int e = 0; e < 4; ++e) {
            const float val = (e == 0) ? v.x : (e == 1) ? v.y : (e == 2) ? v.z : v.w;
            const int   s   = s0 + sl + e;
            float r;
            if (attr == 2) {
                r = __expf(val) * ax;                       // = exp(v)*(ax/8)*8
            } else if (attr == 3) {
                r = __expf(val) * ay;
            } else {
                const float sg = __builtin_amdgcn_rcpf(1.0f + __expf(-val));
                if (attr == 0) {
                    const int x = s % GRID;
                    r = (sg + (float)x) * STRIDE_F;
                } else if (attr == 1) {
                    const int y = s / GRID;
                    r = (sg + (float)y) * STRIDE_F;
                } else {
                    r = sg;
                }
            }
            lds[(sl + e) * CH + c] = r;
        }
    }
    __syncthreads();

    // ---- write phase: output tile is one contiguous [16*255] float region ----
    float* __restrict__ dst = out + (size_t)b * (size_t)(SP * CH) + (size_t)s0 * CH;
    for (int j = tid; j < NF4_READ; j += TPB) {   // 1020 float4 = 16*255 floats
        float4 v = *(const float4*)(lds + j * 4);
        *(float4*)(dst + j * 4) = v;
    }
}

extern "C" void kernel_launch(void* const* d_in, const int* in_sizes, int n_in,
                              void* d_out, int out_size, void* d_ws, size_t ws_size,
                              hipStream_t stream) {
    const float* pred    = (const float*)d_in[0];
    const float* anchors = (const float*)d_in[1];
    float* out = (float*)d_out;

    const int grid = BATCH * TILES_PER_B;   // 32 * 361 = 11552 blocks
    yolo_decode_kernel<<<grid, TPB, 0, stream>>>(pred, anchors, out);
}

// Round 4
// 72.830 us; speedup vs baseline: 1.3969x; 1.1852x over previous
//
#include <hip/hip_runtime.h>

// YOLO decode = batched [255 x 5776] transpose + elementwise, LDS-tiled.
// B=32, A=3, C=80 -> attrs=85, CH=255, G=76, SP=5776, stride=8.
// R4: same as R3 but nontemporal store via native ext_vector_type(4)
//     (__builtin_nontemporal_store rejects HIP_vector_type float4).

#define BATCH   32
#define ATTRS   85
#define CH      255          // A * attrs
#define GRID    76
#define SP      5776         // GRID*GRID
#define STRIDE_F 8.0f
#define S_TILE  32
#define TPB     512
#define TILES_PER_B ((SP + S_TILE - 1) / S_TILE)   // 181 (180 full + one 16-wide)
#define NF4_READ (CH * (S_TILE / 4))               // 255 * 8 = 2040

typedef float f4 __attribute__((ext_vector_type(4)));

__global__ __launch_bounds__(TPB, 8) void yolo_decode_kernel(
        const float* __restrict__ pred,
        const float* __restrict__ anchors,
        float* __restrict__ out) {
    __shared__ float lds[S_TILE * CH];   // transposed tile: [s_local][c], 32KB

    const int tid = threadIdx.x;
    const int bid = blockIdx.x;
    const int b   = bid / TILES_PER_B;
    const int t   = bid - b * TILES_PER_B;
    const int s0  = t * S_TILE;
    const int sw  = (SP - s0 < S_TILE) ? (SP - s0) : S_TILE;  // 32, or 16 on last tile

    // anchors: 6 uniform floats -> registers (L1 broadcast loads)
    const float a0x = anchors[0], a0y = anchors[1];
    const float a1x = anchors[2], a1y = anchors[3];
    const float a2x = anchors[4], a2y = anchors[5];

    // ---- read phase: coalesced float4 loads along spatial, decode, scatter to LDS ----
    const float* __restrict__ src = pred + (size_t)b * (size_t)(CH * SP);
    for (int j = tid; j < NF4_READ; j += TPB) {
        const int c  = j >> 3;          // channel
        const int sl = (j & 7) * 4;     // spatial offset within tile
        if (sl >= sw) continue;         // only trims on the 16-wide partial tile

        f4 v = *(const f4*)(src + c * SP + s0 + sl);

        const int a    = c / ATTRS;     // 0,1,2
        const int attr = c - a * ATTRS;
        const float ax = (a == 0) ? a0x : (a == 1) ? a1x : a2x;
        const float ay = (a == 0) ? a0y : (a == 1) ? a1y : a2y;

        #pragma unroll
        for (int e = 0; e < 4; ++e) {
            const float val = v[e];
            const int   s   = s0 + sl + e;
            float r;
            if (attr == 2) {
                r = __expf(val) * ax;
            } else if (attr == 3) {
                r = __expf(val) * ay;
            } else {
                const float sg = __builtin_amdgcn_rcpf(1.0f + __expf(-val));
                if (attr == 0) {
                    const int x = s % GRID;
                    r = (sg + (float)x) * STRIDE_F;
                } else if (attr == 1) {
                    const int y = s / GRID;
                    r = (sg + (float)y) * STRIDE_F;
                } else {
                    r = sg;
                }
            }
            lds[(sl + e) * CH + c] = r;
        }
    }
    __syncthreads();

    // ---- write phase: output tile is one contiguous [sw*255] float region ----
    const int nf4w = (sw * CH) >> 2;    // 2040 full tile, 1020 partial; both exact
    float* __restrict__ dst = out + (size_t)b * (size_t)(SP * CH) + (size_t)s0 * CH;
    for (int j = tid; j < nf4w; j += TPB) {
        f4 v = *(const f4*)(lds + j * 4);
        __builtin_nontemporal_store(v, (f4*)(dst + j * 4));
    }
}

extern "C" void kernel_launch(void* const* d_in, const int* in_sizes, int n_in,
                              void* d_out, int out_size, void* d_ws, size_t ws_size,
                              hipStream_t stream) {
    const float* pred    = (const float*)d_in[0];
    const float* anchors = (const float*)d_in[1];
    float* out = (float*)d_out;

    const int grid = BATCH * TILES_PER_B;   // 32 * 181 = 5792 blocks
    yolo_decode_kernel<<<grid, TPB, 0, stream>>>(pred, anchors, out);
}

// Round 5
// 68.299 us; speedup vs baseline: 1.4896x; 1.0663x over previous
//
#include <hip/hip_runtime.h>

// YOLO decode = batched [255 x 5776] transpose + elementwise, LDS-tiled.
// B=32, A=3, C=80 -> attrs=85, CH=255, G=76, SP=5776, stride=8.
// R5: S_TILE=64 + TPB=1024 (256B/channel-row reads, 2 blocks/CU = 32 waves/CU,
//     half the blocks), nontemporal f4 stores. LDS 65280B < 64KiB static cap.

#define BATCH   32
#define ATTRS   85
#define CH      255          // A * attrs
#define GRID    76
#define SP      5776         // GRID*GRID; 5776 = 64*90 + 16
#define STRIDE_F 8.0f
#define S_TILE  64
#define TPB     1024
#define TILES_PER_B ((SP + S_TILE - 1) / S_TILE)   // 91 (90 full + one 16-wide)
#define NF4_READ (CH * (S_TILE / 4))               // 255 * 16 = 4080

typedef float f4 __attribute__((ext_vector_type(4)));

__global__ __launch_bounds__(TPB, 8) void yolo_decode_kernel(
        const float* __restrict__ pred,
        const float* __restrict__ anchors,
        float* __restrict__ out) {
    __shared__ float lds[S_TILE * CH];   // transposed tile: [s_local][c], 65280 B

    const int tid = threadIdx.x;
    const int bid = blockIdx.x;
    const int b   = bid / TILES_PER_B;
    const int t   = bid - b * TILES_PER_B;
    const int s0  = t * S_TILE;
    const int sw  = (SP - s0 < S_TILE) ? (SP - s0) : S_TILE;  // 64, or 16 on last tile

    // anchors: 6 uniform floats -> registers (L1 broadcast loads, hoisted)
    const float a0x = anchors[0], a0y = anchors[1];
    const float a1x = anchors[2], a1y = anchors[3];
    const float a2x = anchors[4], a2y = anchors[5];

    // ---- read phase: coalesced f4 loads along spatial, decode, scatter to LDS ----
    const float* __restrict__ src = pred + (size_t)b * (size_t)(CH * SP);
    for (int j = tid; j < NF4_READ; j += TPB) {
        const int c  = j >> 4;           // channel (S_TILE/4 = 16 f4 per row)
        const int sl = (j & 15) * 4;     // spatial offset within tile
        if (sl >= sw) continue;          // only trims on the 16-wide partial tile

        f4 v = *(const f4*)(src + c * SP + s0 + sl);

        const int a    = c / ATTRS;      // 0,1,2
        const int attr = c - a * ATTRS;
        const float ax = (a == 0) ? a0x : (a == 1) ? a1x : a2x;
        const float ay = (a == 0) ? a0y : (a == 1) ? a1y : a2y;

        #pragma unroll
        for (int e = 0; e < 4; ++e) {
            const float val = v[e];
            const int   s   = s0 + sl + e;
            float r;
            if (attr == 2) {
                r = __expf(val) * ax;
            } else if (attr == 3) {
                r = __expf(val) * ay;
            } else {
                const float sg = __builtin_amdgcn_rcpf(1.0f + __expf(-val));
                if (attr == 0) {
                    const int x = s % GRID;
                    r = (sg + (float)x) * STRIDE_F;
                } else if (attr == 1) {
                    const int y = s / GRID;
                    r = (sg + (float)y) * STRIDE_F;
                } else {
                    r = sg;
                }
            }
            lds[(sl + e) * CH + c] = r;
        }
    }
    __syncthreads();

    // ---- write phase: output tile is one contiguous [sw*255] float region ----
    const int nf4w = (sw * CH) >> 2;    // 4080 full tile, 1020 partial; both exact
    float* __restrict__ dst = out + (size_t)b * (size_t)(SP * CH) + (size_t)s0 * CH;
    for (int j = tid; j < nf4w; j += TPB) {
        f4 v = *(const f4*)(lds + j * 4);
        __builtin_nontemporal_store(v, (f4*)(dst + j * 4));
    }
}

extern "C" void kernel_launch(void* const* d_in, const int* in_sizes, int n_in,
                              void* d_out, int out_size, void* d_ws, size_t ws_size,
                              hipStream_t stream) {
    const float* pred    = (const float*)d_in[0];
    const float* anchors = (const float*)d_in[1];
    float* out = (float*)d_out;

    const int grid = BATCH * TILES_PER_B;   // 32 * 91 = 2912 blocks
    yolo_decode_kernel<<<grid, TPB, 0, stream>>>(pred, anchors, out);
}